// Round 2
// baseline (410.324 us; speedup 1.0000x reference)
//
#include <hip/hip_runtime.h>

// Problem constants (fixed by the reference)
#define NTOK 8192
#define BDIM 32
#define GRU  256
#define HAN  512
#define INNER 128
static constexpr float SCALE = 0.08838834764831845f; // 128^-0.5

// ---------------------------------------------------------------------------
// Small fp32 GEMM: C[M x J] = alpha * A[M x K] @ B
//   B_T = false: B is [K x J] row-major (ldb = J)
//   B_T = true : B is [J x K] row-major (ldb = K), accessed transposed
// Block: 512 threads (8 waves), output tile 64(n) x 64(j), 4x2 micro-tile.
// K must be a multiple of 32. grid = (M/64, J/64)
// ---------------------------------------------------------------------------
template <bool B_T>
__global__ __launch_bounds__(512) void gemm_tile(const float* __restrict__ A,
                                                 const float* __restrict__ B,
                                                 float* __restrict__ C,
                                                 int M, int K, int J, float alpha) {
    __shared__ float As[32][68];  // [k][n]; 68*4B keeps float4 rows 16B-aligned
    __shared__ float Bs[32][68];  // [k][j]

    const int t  = threadIdx.x;
    const int n0 = blockIdx.x * 64;
    const int j0 = blockIdx.y * 64;
    const int tn = t >> 5;        // 0..15 -> rows tn*4..tn*4+3
    const int tj = t & 31;        // 0..31 -> cols tj*2, tj*2+1

    // staging coords for A (and transposed-B): 64 rows x 32 k, float4 per lane
    const int r_l = t >> 3;       // 0..63 row within tile
    const int kq  = t & 7;        // 0..7  -> float4 index within 32 k

    float acc[4][2];
#pragma unroll
    for (int i = 0; i < 4; ++i) { acc[i][0] = 0.0f; acc[i][1] = 0.0f; }

    for (int kc = 0; kc < K; kc += 32) {
        // ---- stage A chunk [64 n][32 k], transposed into LDS ----
        {
            const float4 a = *(const float4*)(A + (size_t)(n0 + r_l) * K + kc + kq * 4);
            As[kq * 4 + 0][r_l] = a.x;
            As[kq * 4 + 1][r_l] = a.y;
            As[kq * 4 + 2][r_l] = a.z;
            As[kq * 4 + 3][r_l] = a.w;
        }
        // ---- stage B chunk [32 k][64 j] ----
        if (B_T) {
            const float4 b = *(const float4*)(B + (size_t)(j0 + r_l) * K + kc + kq * 4);
            Bs[kq * 4 + 0][r_l] = b.x;
            Bs[kq * 4 + 1][r_l] = b.y;
            Bs[kq * 4 + 2][r_l] = b.z;
            Bs[kq * 4 + 3][r_l] = b.w;
        } else {
            const int k_l = t >> 4;          // 0..31
            const int j4  = (t & 15) * 4;    // 0..60
            *(float4*)&Bs[k_l][j4] =
                *(const float4*)(B + (size_t)(kc + k_l) * J + j0 + j4);
        }
        __syncthreads();

#pragma unroll
        for (int kk = 0; kk < 32; ++kk) {
            const float4 a4 = *(const float4*)&As[kk][tn * 4];
            const float2 b2 = *(const float2*)&Bs[kk][tj * 2];
            acc[0][0] = fmaf(a4.x, b2.x, acc[0][0]);
            acc[0][1] = fmaf(a4.x, b2.y, acc[0][1]);
            acc[1][0] = fmaf(a4.y, b2.x, acc[1][0]);
            acc[1][1] = fmaf(a4.y, b2.y, acc[1][1]);
            acc[2][0] = fmaf(a4.z, b2.x, acc[2][0]);
            acc[2][1] = fmaf(a4.z, b2.y, acc[2][1]);
            acc[3][0] = fmaf(a4.w, b2.x, acc[3][0]);
            acc[3][1] = fmaf(a4.w, b2.y, acc[3][1]);
        }
        __syncthreads();
    }

#pragma unroll
    for (int i = 0; i < 4; ++i) {
        float2 o;
        o.x = acc[i][0] * alpha;
        o.y = acc[i][1] * alpha;
        *(float2*)(C + (size_t)(n0 + tn * 4 + i) * J + j0 + tj * 2) = o;
    }
}

// ---------------------------------------------------------------------------
// Main streaming kernel: per block, 16 tokens x all 32 batches.
//   sim[b,n] = dot(change[b,n,:], w[n,:])   (scale already folded into w)
//   masked -> -1e9, softmax over b, write out[n,b].
// Block: 512 threads (8 waves). Each wave owns 2 tokens; 32 lanes per token,
// each lane covers 8 floats (32B) of the 256-dim dot.
// grid = NTOK/16 = 512  (2 blocks/CU, 16 waves/CU)
// ---------------------------------------------------------------------------
__global__ __launch_bounds__(512) void cal_sim_main(const float* __restrict__ chg,
                                                    const void* __restrict__ maskp,
                                                    const float* __restrict__ w,
                                                    float* __restrict__ out) {
    __shared__ float sim[BDIM][17];  // padded: conflict-free transposed read
    __shared__ float mrow[16], srow[16];
    __shared__ int mask_is_int;

    const int t  = threadIdx.x;
    const int n0 = blockIdx.x * 16;

    if (t == 0) {
        // Runtime-detect mask ABI: int32 0/1 words vs packed bool bytes.
        // Random bool bytes make a >1 uint word in the first 64 with
        // overwhelming probability; all-zero prefix degrades gracefully
        // (both interpretations agree on zeros we read in-range).
        const unsigned int* mi = (const unsigned int*)maskp;
        int ok = 1;
        for (int i = 0; i < 64; ++i) ok &= (mi[i] <= 1u);
        mask_is_int = ok;
    }

    const int wave = t >> 6;        // 0..7
    const int half = (t >> 5) & 1;  // which of the wave's 2 tokens
    const int dq   = t & 31;        // 8-float slice of dim 256
    const int nloc = wave * 2 + half;
    const int n    = n0 + nloc;

    // w fragment: 2 x float4 = this lane's 8 floats of w[n,:]
    float4 wr0 = *(const float4*)(w + (size_t)n * GRU + dq * 8);
    float4 wr1 = *(const float4*)(w + (size_t)n * GRU + dq * 8 + 4);

    __syncthreads();
    const int misi = mask_is_int;
    const int* mi = (const int*)maskp;
    const unsigned char* mb = (const unsigned char*)maskp;

    for (int b = 0; b < BDIM; ++b) {
        const float* cp = chg + ((size_t)b * NTOK + n) * GRU + dq * 8;
        const float4 c0 = *(const float4*)(cp);
        const float4 c1 = *(const float4*)(cp + 4);
        float p;
        p = c0.x * wr0.x;
        p = fmaf(c0.y, wr0.y, p);
        p = fmaf(c0.z, wr0.z, p);
        p = fmaf(c0.w, wr0.w, p);
        p = fmaf(c1.x, wr1.x, p);
        p = fmaf(c1.y, wr1.y, p);
        p = fmaf(c1.z, wr1.z, p);
        p = fmaf(c1.w, wr1.w, p);
        // reduce across the 32 lanes of this token
        p += __shfl_xor(p, 1, 64);
        p += __shfl_xor(p, 2, 64);
        p += __shfl_xor(p, 4, 64);
        p += __shfl_xor(p, 8, 64);
        p += __shfl_xor(p, 16, 64);
        if (dq == 0) {
            const size_t mofs = (size_t)b * NTOK + n;
            const int mval = misi ? mi[mofs] : (int)mb[mofs];
            sim[b][nloc] = mval ? p : -1e9f;
        }
    }
    __syncthreads();

    // softmax over batch for each of the 16 tokens
    if (t < 16) {
        float m = sim[0][t];
        for (int b = 1; b < BDIM; ++b) m = fmaxf(m, sim[b][t]);
        float s = 0.0f;
        for (int b = 0; b < BDIM; ++b) s += __expf(sim[b][t] - m);
        mrow[t] = m;
        srow[t] = 1.0f / s;
    }
    __syncthreads();

    // write out[n, b]: 512 floats per block, fully coalesced (2KB contiguous)
    {
        const int b  = t & 31;
        const int nl = t >> 5;
        out[(size_t)n0 * BDIM + t] = __expf(sim[b][nl] - mrow[nl]) * srow[nl];
    }
}

extern "C" void kernel_launch(void* const* d_in, const int* in_sizes, int n_in,
                              void* d_out, int out_size, void* d_ws, size_t ws_size,
                              hipStream_t stream) {
    const float* chg   = (const float*)d_in[0];  // [32, 8192, 256]
    const float* edges = (const float*)d_in[1];  // [8192, 512]
    const void*  mask  = d_in[2];                // [32, 8192] bool/int
    const float* Wq    = (const float*)d_in[3];  // [128, 256]
    const float* Wk    = (const float*)d_in[4];  // [128, 512]
    float* out = (float*)d_out;                  // [8192, 32]

    float* kws = (float*)d_ws;                   // [8192, 128] = 4 MB
    float* wws = kws + (size_t)NTOK * INNER;     // [8192, 256] = 8 MB

    // k = edges @ Wk.T            (B transposed access)
    gemm_tile<true><<<dim3(NTOK / 64, INNER / 64), 512, 0, stream>>>(
        edges, Wk, kws, NTOK, HAN, INNER, 1.0f);

    // w = SCALE * k @ Wq          (B natural [K x J] layout)
    gemm_tile<false><<<dim3(NTOK / 64, GRU / 64), 512, 0, stream>>>(
        kws, Wq, wws, NTOK, INNER, GRU, SCALE);

    // sim + mask + softmax(batch) + transposed write
    cal_sim_main<<<NTOK / 16, 512, 0, stream>>>(chg, mask, wws, out);
}

// Round 5
// 408.090 us; speedup vs baseline: 1.0055x; 1.0055x over previous
//
#include <hip/hip_runtime.h>

// Problem constants (fixed by the reference)
#define NTOK 8192
#define BDIM 32
#define GRU  256
#define HAN  512
#define INNER 128
static constexpr float SCALE = 0.08838834764831845f; // 128^-0.5

// ---------------------------------------------------------------------------
// K1: M[e][j] = SCALE * sum_i Wk[i][e] * Wq[i][j]      (M: [512][256])
// grid = 512 blocks x 256 threads; block e, thread j. 33.5 MFLOP total.
// Block 0 / wave 0 also computes the mask-ABI flag (int32 words vs bool
// bytes): 64 leading uint words all <=1  <=> int32 mask.
// ---------------------------------------------------------------------------
__global__ __launch_bounds__(256) void make_m(const float* __restrict__ Wk,
                                              const float* __restrict__ Wq,
                                              const void* __restrict__ maskp,
                                              float* __restrict__ M,
                                              int* __restrict__ flag) {
    const int e = blockIdx.x;     // 0..511
    const int j = threadIdx.x;    // 0..255
    float acc = 0.0f;
#pragma unroll 8
    for (int i = 0; i < INNER; ++i)
        acc = fmaf(Wk[(size_t)i * HAN + e], Wq[(size_t)i * GRU + j], acc);
    M[(size_t)e * GRU + j] = SCALE * acc;

    if (e == 0 && j < 64) {
        const unsigned int* mi = (const unsigned int*)maskp;
        const int ok = __all((int)(mi[j] <= 1u)) ? 1 : 0;
        if (j == 0) *flag = ok;
    }
}

// ---------------------------------------------------------------------------
// K2: C[M x J] = A[M x K] @ B[K x J]   (w = edges @ M)
// 256 threads (4 waves), 64x64 output tile, 4x4 micro-tile (16x16 thread
// grid), BK=32. LDS bytes/FLOP = 1.0 (32B per 16 FMA per thread).
// grid = (M/64, J/64) = (128, 4) = 512 blocks -> 2 blocks/CU, 8 waves/CU.
// ---------------------------------------------------------------------------
__global__ __launch_bounds__(256) void gemm_tile(const float* __restrict__ A,
                                                 const float* __restrict__ B,
                                                 float* __restrict__ C,
                                                 int M, int K, int J) {
    __shared__ float As[32][68];  // [k][n]; 68 keeps float4 rows 16B-aligned
    __shared__ float Bs[32][68];  // [k][j]

    const int t  = threadIdx.x;
    const int n0 = blockIdx.x * 64;
    const int j0 = blockIdx.y * 64;
    const int tn = t >> 4;        // 0..15 -> rows tn*4..tn*4+3
    const int tj = t & 15;        // 0..15 -> cols tj*4..tj*4+3

    // A staging: 64 rows x 32 k = 512 float4, 2 per thread
    const int r_l = t >> 2;       // 0..63 row within tile
    const int kq  = t & 3;        // float4 index within first 16 k
    // B staging: 32 k x 64 j = 512 float4, 2 per thread
    const int k_l = t >> 4;       // 0..15
    const int j4  = (t & 15) * 4; // 0..60

    float acc[4][4];
#pragma unroll
    for (int i = 0; i < 4; ++i)
#pragma unroll
        for (int j = 0; j < 4; ++j) acc[i][j] = 0.0f;

    for (int kc = 0; kc < K; kc += 32) {
        // stage A chunk [64 n][32 k], transposed into LDS (two float4/thread)
#pragma unroll
        for (int h = 0; h < 2; ++h) {
            const int kb = kq * 4 + h * 16;
            const float4 a = *(const float4*)(A + (size_t)(n0 + r_l) * K + kc + kb);
            As[kb + 0][r_l] = a.x;
            As[kb + 1][r_l] = a.y;
            As[kb + 2][r_l] = a.z;
            As[kb + 3][r_l] = a.w;
        }
        // stage B chunk [32 k][64 j] (two float4/thread)
#pragma unroll
        for (int h = 0; h < 2; ++h) {
            const int kr = k_l + h * 16;
            *(float4*)&Bs[kr][j4] =
                *(const float4*)(B + (size_t)(kc + kr) * J + j0 + j4);
        }
        __syncthreads();

#pragma unroll
        for (int kk = 0; kk < 32; ++kk) {
            const float4 a4 = *(const float4*)&As[kk][tn * 4];
            const float4 b4 = *(const float4*)&Bs[kk][tj * 4];
            const float av[4] = {a4.x, a4.y, a4.z, a4.w};
            const float bv[4] = {b4.x, b4.y, b4.z, b4.w};
#pragma unroll
            for (int i = 0; i < 4; ++i)
#pragma unroll
                for (int j = 0; j < 4; ++j)
                    acc[i][j] = fmaf(av[i], bv[j], acc[i][j]);
        }
        __syncthreads();
    }

#pragma unroll
    for (int i = 0; i < 4; ++i) {
        float4 o;
        o.x = acc[i][0];
        o.y = acc[i][1];
        o.z = acc[i][2];
        o.w = acc[i][3];
        *(float4*)(C + (size_t)(n0 + tn * 4 + i) * J + j0 + tj * 4) = o;
    }
}

// ---------------------------------------------------------------------------
// K3: streaming main. Per block: 16 tokens x all 32 batches.
//   sim[b,n] = dot(change[b,n,:], w[n,:])   (scale already folded into M)
//   masked -> -1e9, softmax over b, write out[n,b].
// Block: 512 threads (8 waves); wave owns 2 tokens, 32 lanes/token,
// 8 floats (32B) per lane of the 256-dim dot. grid = 512 (2 blocks/CU).
// b-loop unrolled x8: 16 dwordx4 loads in flight per lane (256B) for HBM
// latency hiding at 16 waves/CU.
// ---------------------------------------------------------------------------
__global__ __launch_bounds__(512) void cal_sim_main(const float* __restrict__ chg,
                                                    const void* __restrict__ maskp,
                                                    const float* __restrict__ w,
                                                    const int* __restrict__ flag,
                                                    float* __restrict__ out) {
    __shared__ float sim[BDIM][17];  // padded: conflict-free transposed read
    __shared__ float mrow[16], srow[16];

    const int t  = threadIdx.x;
    const int n0 = blockIdx.x * 16;

    const int wave = t >> 6;        // 0..7
    const int half = (t >> 5) & 1;  // which of the wave's 2 tokens
    const int dq   = t & 31;        // 8-float slice of dim 256
    const int nloc = wave * 2 + half;
    const int n    = n0 + nloc;

    // this lane's 8 floats of w[n,:]
    const float4 wr0 = *(const float4*)(w + (size_t)n * GRU + dq * 8);
    const float4 wr1 = *(const float4*)(w + (size_t)n * GRU + dq * 8 + 4);

    const int misi = *flag;         // uniform
    const int* mi = (const int*)maskp;
    const unsigned char* mb = (const unsigned char*)maskp;

#pragma unroll 8
    for (int b = 0; b < BDIM; ++b) {
        const float* cp = chg + ((size_t)b * NTOK + n) * GRU + dq * 8;
        const float4 c0 = *(const float4*)(cp);
        const float4 c1 = *(const float4*)(cp + 4);
        float p;
        p = c0.x * wr0.x;
        p = fmaf(c0.y, wr0.y, p);
        p = fmaf(c0.z, wr0.z, p);
        p = fmaf(c0.w, wr0.w, p);
        p = fmaf(c1.x, wr1.x, p);
        p = fmaf(c1.y, wr1.y, p);
        p = fmaf(c1.z, wr1.z, p);
        p = fmaf(c1.w, wr1.w, p);
        // reduce across the 32 lanes of this token
        p += __shfl_xor(p, 1, 64);
        p += __shfl_xor(p, 2, 64);
        p += __shfl_xor(p, 4, 64);
        p += __shfl_xor(p, 8, 64);
        p += __shfl_xor(p, 16, 64);
        if (dq == 0) {
            const size_t mofs = (size_t)b * NTOK + n;
            const int mval = misi ? mi[mofs] : (int)mb[mofs];
            sim[b][nloc] = mval ? p : -1e9f;
        }
    }
    __syncthreads();

    // softmax over batch for each of the 16 tokens
    if (t < 16) {
        float m = sim[0][t];
        for (int b = 1; b < BDIM; ++b) m = fmaxf(m, sim[b][t]);
        float s = 0.0f;
        for (int b = 0; b < BDIM; ++b) s += __expf(sim[b][t] - m);
        mrow[t] = m;
        srow[t] = 1.0f / s;
    }
    __syncthreads();

    // write out[n, b]: 512 floats per block, fully coalesced (2KB contiguous)
    {
        const int b  = t & 31;
        const int nl = t >> 5;
        out[(size_t)n0 * BDIM + t] = __expf(sim[b][nl] - mrow[nl]) * srow[nl];
    }
}

extern "C" void kernel_launch(void* const* d_in, const int* in_sizes, int n_in,
                              void* d_out, int out_size, void* d_ws, size_t ws_size,
                              hipStream_t stream) {
    const float* chg   = (const float*)d_in[0];  // [32, 8192, 256]
    const float* edges = (const float*)d_in[1];  // [8192, 512]
    const void*  mask  = d_in[2];                // [32, 8192] bool/int
    const float* Wq    = (const float*)d_in[3];  // [128, 256]
    const float* Wk    = (const float*)d_in[4];  // [128, 512]
    float* out = (float*)d_out;                  // [8192, 32]

    float* wws  = (float*)d_ws;                    // [8192][256] = 8 MB
    float* Mws  = wws + (size_t)NTOK * GRU;        // [512][256]  = 512 KB
    int*   flag = (int*)(Mws + (size_t)HAN * GRU); // 4 B

    // K1: M = SCALE * Wk^T @ Wq  (+ mask ABI flag)
    make_m<<<HAN, 256, 0, stream>>>(Wk, Wq, mask, Mws, flag);

    // K2: w = edges @ M          ([8192,512] @ [512,256])
    gemm_tile<<<dim3(NTOK / 64, GRU / 64), 256, 0, stream>>>(
        edges, Mws, wws, NTOK, HAN, GRU);

    // K3: sim + mask + softmax(batch) + transposed write
    cal_sim_main<<<NTOK / 16, 512, 0, stream>>>(chg, mask, wws, flag, out);
}